// Round 2
// baseline (1033.326 us; speedup 1.0000x reference)
//
#include <hip/hip_runtime.h>

#define BB 16
#define NN 2048
#define MM 2048
#define EPSF 1e-9f

constexpr int WAVES = 4;   // waves per block
constexpr int RB = 8;      // rows per wave (row passes)
constexpr int CB = 8;      // cols per wave (col pass)

// Workspace layout:
//  P1[b*NN+i] = float4(x1, y1, z1, scale_i)   -- scale written by row_pass
//  P2[b*MM+l] = float4(x2, y2, z2, remR_l)    -- remR  written by col_pass
//  remL[b*NN+i]
//  Pcol[b*MM+l] = remR_l * cons_l             -- written by col_pass

// ---------------- init: AoS->packed float4 + state init ----------------
__global__ __launch_bounds__(256) void init_kernel(
    const float* __restrict__ xyz1, const float* __restrict__ xyz2,
    float4* __restrict__ P1, float4* __restrict__ P2,
    float* __restrict__ remL, float* __restrict__ out)
{
    const int t = blockIdx.x * 256 + threadIdx.x;
    if (t < BB * NN) {
        P1[t] = make_float4(xyz1[3*t+0], xyz1[3*t+1], xyz1[3*t+2], 0.0f);
        remL[t] = 1.0f;   // max(n,m)/n
    }
    if (t < BB * MM) {
        P2[t] = make_float4(xyz2[3*t+0], xyz2[3*t+1], xyz2[3*t+2], 1.0f); // .w = remR
    }
    if (t < BB) out[t] = 0.0f;
}

// ---------------- row pass ----------------
// MODE 0: first pass. rowsum at coefNext only (remL == 1 from init).
// MODE 1: fused remainL-update (level j, via e_next^4) + new scale (level j+1).
// MODE 2: last fused pass: e_prev = exp2(coefPrev*d2) direct, e_next = 1 (level 0).
template<int MODE>
__global__ __launch_bounds__(256) void row_pass(
    const float4* __restrict__ P2, const float* __restrict__ Pcol,
    float4* __restrict__ P1, float* __restrict__ remL,
    float coefPrev, float coefNext)
{
    const int lane = threadIdx.x & 63;
    const int wave = threadIdx.x >> 6;
    const int bpb = NN / (WAVES * RB);          // blocks per batch = 64
    const int batch = blockIdx.x / bpb;
    const int rblk  = blockIdx.x % bpb;
    const int r0 = rblk * (WAVES * RB) + wave * RB;

    const float4* p1b = P1 + batch * NN;
    float px[RB], py[RB], pz[RB], psc[RB];
#pragma unroll
    for (int r = 0; r < RB; ++r) {
        const float4 q = p1b[r0 + r];
        px[r] = q.x; py[r] = q.y; pz[r] = q.z;
        psc[r] = (MODE != 0) ? q.w : 0.0f;      // previous scale
    }

    const float4* p2b = P2 + batch * MM;
    const float* pcb  = Pcol + batch * MM;

    float u[RB], rs[RB];
#pragma unroll
    for (int r = 0; r < RB; ++r) { u[r] = 0.0f; rs[r] = 0.0f; }

#pragma unroll 4
    for (int c = lane; c < MM; c += 64) {
        const float4 q = p2b[c];                // x,y,z,remR
        const float Rn = q.w;
        const float Pc = (MODE != 0) ? pcb[c] : 0.0f;
        if (MODE == 2) rs[0] += Rn;             // e_next = 1, r-independent
#pragma unroll
        for (int r = 0; r < RB; ++r) {
            const float dx = px[r] - q.x, dy = py[r] - q.y, dz = pz[r] - q.z;
            const float d2 = dx*dx + dy*dy + dz*dz;
            if (MODE == 0) {
                rs[r] = fmaf(__builtin_amdgcn_exp2f(coefNext * d2), Rn, rs[r]);
            } else if (MODE == 1) {
                const float en = __builtin_amdgcn_exp2f(coefNext * d2);
                const float e2 = en * en;
                u[r]  = fmaf(e2 * e2, Pc, u[r]);   // e_prev = e_next^4
                rs[r] = fmaf(en, Rn, rs[r]);
            } else {
                const float ep = __builtin_amdgcn_exp2f(coefPrev * d2);
                u[r]  = fmaf(ep, Pc, u[r]);
            }
        }
    }

#pragma unroll
    for (int r = 0; r < RB; ++r) {
#pragma unroll
        for (int off = 32; off > 0; off >>= 1) {
            if (MODE != 2 || r == 0) rs[r] += __shfl_xor(rs[r], off, 64);
            if (MODE != 0) u[r] += __shfl_xor(u[r], off, 64);
        }
    }

    float* p1w = (float*)P1;                    // scalar access to .w lanes
#pragma unroll
    for (int r = 0; r < RB; ++r) {
        if (lane == r) {
            const int row = batch * NN + r0 + r;
            const float rsum = (MODE == 2) ? rs[0] : rs[r];
            float L;
            if (MODE == 0) {
                L = remL[row];
            } else {
                L = fmaxf(remL[row] - psc[r] * u[r], 0.0f);
                remL[row] = L;
            }
            p1w[4 * row + 3] = L / (rsum + EPSF);   // scale
        }
    }
}

// ---------------- col pass ----------------
__global__ __launch_bounds__(256) void col_pass(
    const float4* __restrict__ P1,
    float4* __restrict__ P2, float* __restrict__ Pcol,
    float* __restrict__ out, float coef)
{
    const int lane = threadIdx.x & 63;
    const int wave = threadIdx.x >> 6;
    const int bpb = MM / (WAVES * CB);          // 64
    const int batch = blockIdx.x / bpb;
    const int cblk  = blockIdx.x % bpb;
    const int c0 = cblk * (WAVES * CB) + wave * CB;

    const float4* p2b = P2 + batch * MM;
    float qx[CB], qy[CB], qz[CB];
#pragma unroll
    for (int cc = 0; cc < CB; ++cc) {
        const float4 q = p2b[c0 + cc];
        qx[cc] = q.x; qy[cc] = q.y; qz[cc] = q.z;
    }

    const float4* p1b = P1 + batch * NN;

    float s[CB], t[CB];
#pragma unroll
    for (int cc = 0; cc < CB; ++cc) { s[cc] = 0.0f; t[cc] = 0.0f; }

#pragma unroll 4
    for (int i = lane; i < NN; i += 64) {
        const float4 a = p1b[i];                // x,y,z,scale
        const float si = a.w;
#pragma unroll
        for (int cc = 0; cc < CB; ++cc) {
            const float dx = a.x - qx[cc], dy = a.y - qy[cc], dz = a.z - qz[cc];
            const float d2 = dx*dx + dy*dy + dz*dz;
            const float e  = __builtin_amdgcn_exp2f(coef * d2);
            const float se = si * e;
            s[cc] += se;
            t[cc] = fmaf(se, __builtin_amdgcn_sqrtf(d2), t[cc]);
        }
    }

#pragma unroll
    for (int cc = 0; cc < CB; ++cc) {
#pragma unroll
        for (int off = 32; off > 0; off >>= 1) {
            s[cc] += __shfl_xor(s[cc], off, 64);
            t[cc] += __shfl_xor(t[cc], off, 64);
        }
    }

    float* p2w = (float*)P2;
    float costw = 0.0f;
#pragma unroll
    for (int cc = 0; cc < CB; ++cc) {
        if (lane == cc) {
            const int col = batch * MM + c0 + cc;
            const float R = p2w[4 * col + 3];   // remR
            const float sumr = s[cc] * R;
            const float cons = fminf(R / (sumr + EPSF), 1.0f);
            costw = R * cons * t[cc];
            Pcol[col] = R * cons;
            p2w[4 * col + 3] = fmaxf(R - sumr * cons, 0.0f);
        }
    }
#pragma unroll
    for (int off = 32; off > 0; off >>= 1) costw += __shfl_xor(costw, off, 64);
    if (lane == 0) atomicAdd(out + batch, costw);
}

extern "C" void kernel_launch(void* const* d_in, const int* in_sizes, int n_in,
                              void* d_out, int out_size, void* d_ws, size_t ws_size,
                              hipStream_t stream)
{
    const float* xyz1 = (const float*)d_in[0];
    const float* xyz2 = (const float*)d_in[1];
    float* out = (float*)d_out;

    const int BN = BB * NN, BM = BB * MM;
    float4* P1 = (float4*)d_ws;
    float4* P2 = P1 + BN;
    float*  remL = (float*)(P2 + BM);
    float*  Pcol = remL + BN;

    init_kernel<<<dim3((BN + 255) / 256), dim3(256), 0, stream>>>(
        xyz1, xyz2, P1, P2, remL, out);

    // levels: j = 7..-1 -> -(4^j), then 0.  coef = level * log2(e)
    float coef[10];
    const double lv[10] = {-16384.0, -4096.0, -1024.0, -256.0, -64.0,
                           -16.0, -4.0, -1.0, -0.25, 0.0};
    for (int i = 0; i < 10; ++i) coef[i] = (float)(lv[i] * 1.4426950408889634);

    dim3 grid(BB * (NN / (WAVES * RB)));   // 1024
    dim3 blk(256);

    row_pass<0><<<grid, blk, 0, stream>>>(P2, Pcol, P1, remL, 0.0f, coef[0]);
    for (int j = 0; j < 10; ++j) {
        col_pass<<<grid, blk, 0, stream>>>(P1, P2, Pcol, out, coef[j]);
        if (j < 8) {
            row_pass<1><<<grid, blk, 0, stream>>>(P2, Pcol, P1, remL, coef[j], coef[j+1]);
        } else if (j == 8) {
            row_pass<2><<<grid, blk, 0, stream>>>(P2, Pcol, P1, remL, coef[8], 0.0f);
        }
    }
}

// Round 3
// 940.574 us; speedup vs baseline: 1.0986x; 1.0986x over previous
//
#include <hip/hip_runtime.h>

#define BB 16
#define NN 2048
#define MM 2048
#define EPSF 1e-9f

constexpr int WAVES = 4;   // waves per block
constexpr int RB = 8;      // rows per wave (row passes)
constexpr int CB = 8;      // cols per wave (col pass)

// Workspace layout:
//  P1[b*NN+i] = float4(x1, y1, z1, scale_i)   -- scale written by row_pass
//  P2[b*MM+l] = float4(x2, y2, z2, remR_l)    -- remR  written by col_pass
//  remL[b*NN+i]
//  Pcol[b*MM+l] = remR_l * cons_l             -- written by col_pass

// ---------------- init: AoS->packed float4 + state init ----------------
__global__ __launch_bounds__(256) void init_kernel(
    const float* __restrict__ xyz1, const float* __restrict__ xyz2,
    float4* __restrict__ P1, float4* __restrict__ P2,
    float* __restrict__ remL, float* __restrict__ out)
{
    const int t = blockIdx.x * 256 + threadIdx.x;
    if (t < BB * NN) {
        P1[t] = make_float4(xyz1[3*t+0], xyz1[3*t+1], xyz1[3*t+2], 0.0f);
        remL[t] = 1.0f;   // max(n,m)/n
    }
    if (t < BB * MM) {
        P2[t] = make_float4(xyz2[3*t+0], xyz2[3*t+1], xyz2[3*t+2], 1.0f); // .w = remR
    }
    if (t < BB) out[t] = 0.0f;
}

// ---------------- row pass ----------------
// MODE 0: first pass. rowsum at coefNext only (remL == 1 from init).
// MODE 1: fused remainL-update (level j, via e_next^4) + new scale (level j+1).
// MODE 2: last fused pass: e_prev = exp2(coefPrev*d2) direct, e_next = 1 (level 0).
template<int MODE>
__global__ __launch_bounds__(256) void row_pass(
    const float4* __restrict__ P2, const float* __restrict__ Pcol,
    float4* __restrict__ P1, float* __restrict__ remL,
    float coefPrev, float coefNext)
{
    __shared__ float4 sP2[MM];     // 32 KB: x2,y2,z2,remR
    __shared__ float  sPc[MM];     // 8 KB:  remR*cons

    const int lane = threadIdx.x & 63;
    const int wave = threadIdx.x >> 6;
    const int bpb = NN / (WAVES * RB);          // blocks per batch = 64
    const int batch = blockIdx.x / bpb;
    const int rblk  = blockIdx.x % bpb;
    const int r0 = rblk * (WAVES * RB) + wave * RB;

    // ---- stage the streamed arrays into LDS (coalesced) ----
    {
        const float4* p2b = P2 + batch * MM;
        const float*  pcb = Pcol + batch * MM;
        for (int t = threadIdx.x; t < MM; t += 256) {
            sP2[t] = p2b[t];
            if (MODE != 0) sPc[t] = pcb[t];
        }
    }

    const float4* p1b = P1 + batch * NN;
    float px[RB], py[RB], pz[RB], psc[RB];
#pragma unroll
    for (int r = 0; r < RB; ++r) {
        const float4 q = p1b[r0 + r];
        px[r] = q.x; py[r] = q.y; pz[r] = q.z;
        psc[r] = (MODE != 0) ? q.w : 0.0f;      // previous scale
    }

    __syncthreads();

    float u[RB], rs[RB];
#pragma unroll
    for (int r = 0; r < RB; ++r) { u[r] = 0.0f; rs[r] = 0.0f; }

#pragma unroll 4
    for (int c = lane; c < MM; c += 64) {
        const float4 q = sP2[c];                // x,y,z,remR
        const float Rn = q.w;
        const float Pc = (MODE != 0) ? sPc[c] : 0.0f;
        if (MODE == 2) rs[0] += Rn;             // e_next = 1, r-independent
#pragma unroll
        for (int r = 0; r < RB; ++r) {
            const float dx = px[r] - q.x, dy = py[r] - q.y, dz = pz[r] - q.z;
            const float d2 = dx*dx + dy*dy + dz*dz;
            if (MODE == 0) {
                rs[r] = fmaf(__builtin_amdgcn_exp2f(coefNext * d2), Rn, rs[r]);
            } else if (MODE == 1) {
                const float en = __builtin_amdgcn_exp2f(coefNext * d2);
                const float e2 = en * en;
                u[r]  = fmaf(e2 * e2, Pc, u[r]);   // e_prev = e_next^4
                rs[r] = fmaf(en, Rn, rs[r]);
            } else {
                const float ep = __builtin_amdgcn_exp2f(coefPrev * d2);
                u[r]  = fmaf(ep, Pc, u[r]);
            }
        }
    }

#pragma unroll
    for (int r = 0; r < RB; ++r) {
#pragma unroll
        for (int off = 32; off > 0; off >>= 1) {
            if (MODE != 2 || r == 0) rs[r] += __shfl_xor(rs[r], off, 64);
            if (MODE != 0) u[r] += __shfl_xor(u[r], off, 64);
        }
    }

    float* p1w = (float*)P1;                    // scalar access to .w lanes
#pragma unroll
    for (int r = 0; r < RB; ++r) {
        if (lane == r) {
            const int row = batch * NN + r0 + r;
            const float rsum = (MODE == 2) ? rs[0] : rs[r];
            float L;
            if (MODE == 0) {
                L = remL[row];
            } else {
                L = fmaxf(remL[row] - psc[r] * u[r], 0.0f);
                remL[row] = L;
            }
            p1w[4 * row + 3] = L / (rsum + EPSF);   // scale
        }
    }
}

// ---------------- col pass ----------------
__global__ __launch_bounds__(256) void col_pass(
    const float4* __restrict__ P1,
    float4* __restrict__ P2, float* __restrict__ Pcol,
    float* __restrict__ out, float coef)
{
    __shared__ float4 sP1[NN];     // 32 KB: x1,y1,z1,scale

    const int lane = threadIdx.x & 63;
    const int wave = threadIdx.x >> 6;
    const int bpb = MM / (WAVES * CB);          // 64
    const int batch = blockIdx.x / bpb;
    const int cblk  = blockIdx.x % bpb;
    const int c0 = cblk * (WAVES * CB) + wave * CB;

    // ---- stage P1 into LDS (coalesced) ----
    {
        const float4* p1b = P1 + batch * NN;
        for (int t = threadIdx.x; t < NN; t += 256) sP1[t] = p1b[t];
    }

    const float4* p2b = P2 + batch * MM;
    float qx[CB], qy[CB], qz[CB];
#pragma unroll
    for (int cc = 0; cc < CB; ++cc) {
        const float4 q = p2b[c0 + cc];
        qx[cc] = q.x; qy[cc] = q.y; qz[cc] = q.z;
    }

    __syncthreads();

    float s[CB], t[CB];
#pragma unroll
    for (int cc = 0; cc < CB; ++cc) { s[cc] = 0.0f; t[cc] = 0.0f; }

#pragma unroll 4
    for (int i = lane; i < NN; i += 64) {
        const float4 a = sP1[i];                // x,y,z,scale
        const float si = a.w;
#pragma unroll
        for (int cc = 0; cc < CB; ++cc) {
            const float dx = a.x - qx[cc], dy = a.y - qy[cc], dz = a.z - qz[cc];
            const float d2 = dx*dx + dy*dy + dz*dz;
            const float e  = __builtin_amdgcn_exp2f(coef * d2);
            const float se = si * e;
            s[cc] += se;
            t[cc] = fmaf(se, __builtin_amdgcn_sqrtf(d2), t[cc]);
        }
    }

#pragma unroll
    for (int cc = 0; cc < CB; ++cc) {
#pragma unroll
        for (int off = 32; off > 0; off >>= 1) {
            s[cc] += __shfl_xor(s[cc], off, 64);
            t[cc] += __shfl_xor(t[cc], off, 64);
        }
    }

    float* p2w = (float*)P2;
    float costw = 0.0f;
#pragma unroll
    for (int cc = 0; cc < CB; ++cc) {
        if (lane == cc) {
            const int col = batch * MM + c0 + cc;
            const float R = p2w[4 * col + 3];   // remR
            const float sumr = s[cc] * R;
            const float cons = fminf(R / (sumr + EPSF), 1.0f);
            costw = R * cons * t[cc];
            Pcol[col] = R * cons;
            p2w[4 * col + 3] = fmaxf(R - sumr * cons, 0.0f);
        }
    }
#pragma unroll
    for (int off = 32; off > 0; off >>= 1) costw += __shfl_xor(costw, off, 64);
    if (lane == 0) atomicAdd(out + batch, costw);
}

extern "C" void kernel_launch(void* const* d_in, const int* in_sizes, int n_in,
                              void* d_out, int out_size, void* d_ws, size_t ws_size,
                              hipStream_t stream)
{
    const float* xyz1 = (const float*)d_in[0];
    const float* xyz2 = (const float*)d_in[1];
    float* out = (float*)d_out;

    const int BN = BB * NN, BM = BB * MM;
    float4* P1 = (float4*)d_ws;
    float4* P2 = P1 + BN;
    float*  remL = (float*)(P2 + BM);
    float*  Pcol = remL + BN;

    init_kernel<<<dim3((BN + 255) / 256), dim3(256), 0, stream>>>(
        xyz1, xyz2, P1, P2, remL, out);

    // levels: j = 7..-1 -> -(4^j), then 0.  coef = level * log2(e)
    float coef[10];
    const double lv[10] = {-16384.0, -4096.0, -1024.0, -256.0, -64.0,
                           -16.0, -4.0, -1.0, -0.25, 0.0};
    for (int i = 0; i < 10; ++i) coef[i] = (float)(lv[i] * 1.4426950408889634);

    dim3 grid(BB * (NN / (WAVES * RB)));   // 1024
    dim3 blk(256);

    row_pass<0><<<grid, blk, 0, stream>>>(P2, Pcol, P1, remL, 0.0f, coef[0]);
    for (int j = 0; j < 10; ++j) {
        col_pass<<<grid, blk, 0, stream>>>(P1, P2, Pcol, out, coef[j]);
        if (j < 8) {
            row_pass<1><<<grid, blk, 0, stream>>>(P2, Pcol, P1, remL, coef[j], coef[j+1]);
        } else if (j == 8) {
            row_pass<2><<<grid, blk, 0, stream>>>(P2, Pcol, P1, remL, coef[8], 0.0f);
        }
    }
}